// Round 9
// baseline (985.496 us; speedup 1.0000x reference)
//
#include <hip/hip_runtime.h>

#define NEG_INF (-__builtin_huge_valf())
#define NEG_INF_BITS 0xFF800000

#define CCH   4
#define HB    4
#define ROWS  (HB + 2)
#define XSTR  64
#define ESTR  40
#define SLOTS 6

template <int CTRL>
__device__ __forceinline__ float dpp_neighbor(float v) {
    return __int_as_float(__builtin_amdgcn_update_dpp(
        (int)NEG_INF_BITS, __float_as_int(v), CTRL, 0xF, 0xF, false));
}

// ===================== VARIANT A: round-0 verbatim (es edge array) ==========
__global__ __launch_bounds__(64, 4)
void maxplus_a_es(const float* __restrict__ x, const float* __restrict__ kern,
                  float* __restrict__ out) {
    __shared__ float xs[CCH * ROWS * XSTR];
    __shared__ float es[CCH * ROWS * ESTR];

    const int tid = threadIdx.x;
    const int wg  = tid & 15;
    const int hr  = tid >> 4;
    const int w0  = wg << 2;

    const int h_base = blockIdx.x * HB;
    const int b      = blockIdx.y;
    const int o_base = blockIdx.z << 1;

    const float* xb = x + (size_t)b * 64 * 64 * 64;
    const float* gsrc[SLOTS];
    float*       xdst[SLOTS];
    float*       edst[SLOTS];
    bool         vmask[SLOTS];
#pragma unroll
    for (int k = 0; k < SLOTS; ++k) {
        int rowid = k * 4 + hr;
        int cl    = rowid / ROWS;
        int r     = rowid - cl * ROWS;
        int gh    = h_base + r - 1;
        bool valid = (unsigned)gh < 64u;
        int  ghc   = valid ? gh : 0;
        gsrc[k]  = xb + ((size_t)cl * 64 + ghc) * 64 + wg * 4;
        xdst[k]  = &xs[rowid * XSTR + wg * 4];
        edst[k]  = &es[rowid * ESTR + wg];
        vmask[k] = valid;
    }

    if (tid < CCH * ROWS) {
        es[tid * ESTR + 0]  = NEG_INF;
        es[tid * ESTR + 34] = NEG_INF;
    }

    float acc[2][4];
#pragma unroll
    for (int oo = 0; oo < 2; ++oo)
#pragma unroll
        for (int wi = 0; wi < 4; ++wi) acc[oo][wi] = NEG_INF;

    float4 R[SLOTS];
#pragma unroll
    for (int k = 0; k < SLOTS; ++k) R[k] = *(const float4*)gsrc[k];

#pragma unroll 1
    for (int cc = 0; cc < 64; cc += CCH) {
        __syncthreads();
#pragma unroll
        for (int k = 0; k < SLOTS; ++k) {
            float4 v = R[k];
            if (!vmask[k]) v = make_float4(NEG_INF, NEG_INF, NEG_INF, NEG_INF);
            *(float4*)xdst[k] = v;
            edst[k][1]  = v.w;
            edst[k][18] = v.x;
        }
        __syncthreads();

        if (cc + CCH < 64) {
#pragma unroll
            for (int k = 0; k < SLOTS; ++k) {
                gsrc[k] += CCH * 64 * 64;
                R[k] = *(const float4*)gsrc[k];
            }
        }

        float kv[CCH][2][9];
#pragma unroll
        for (int cl = 0; cl < CCH; ++cl)
#pragma unroll
            for (int oo = 0; oo < 2; ++oo) {
                const float* kp = kern + ((size_t)(o_base + oo) * 64 + (cc + cl)) * 9;
#pragma unroll
                for (int t = 0; t < 9; ++t) kv[cl][oo][t] = kp[t];
            }

#pragma unroll
        for (int cl = 0; cl < CCH; ++cl) {
            float xv[3][6];
#pragma unroll
            for (int r = 0; r < 3; ++r) {
                const int rowid = cl * ROWS + hr + r;
                float4 m = *(const float4*)(&xs[rowid * XSTR + w0]);
                const float* ep = &es[rowid * ESTR + wg];
                xv[r][0] = ep[0];
                xv[r][5] = ep[19];
                xv[r][1] = m.x; xv[r][2] = m.y; xv[r][3] = m.z; xv[r][4] = m.w;
            }
#pragma unroll
            for (int oo = 0; oo < 2; ++oo) {
                const float* k9 = kv[cl][oo];
#pragma unroll
                for (int wi = 0; wi < 4; ++wi) {
                    float m = acc[oo][wi];
                    float t0 = xv[0][wi + 0] + k9[0];
                    float t1 = xv[0][wi + 1] + k9[1];
                    m = fmaxf(m, fmaxf(t0, t1));
                    t0 = xv[0][wi + 2] + k9[2];
                    t1 = xv[1][wi + 0] + k9[3];
                    m = fmaxf(m, fmaxf(t0, t1));
                    t0 = xv[1][wi + 1] + k9[4];
                    t1 = xv[1][wi + 2] + k9[5];
                    m = fmaxf(m, fmaxf(t0, t1));
                    t0 = xv[2][wi + 0] + k9[6];
                    t1 = xv[2][wi + 1] + k9[7];
                    m = fmaxf(m, fmaxf(t0, t1));
                    m = fmaxf(m, xv[2][wi + 2] + k9[8]);
                    acc[oo][wi] = m;
                }
            }
        }
    }

    const int h = h_base + hr;
#pragma unroll
    for (int oo = 0; oo < 2; ++oo) {
        float4 v = make_float4(acc[oo][0], acc[oo][1], acc[oo][2], acc[oo][3]);
        *(float4*)(out + ((((size_t)b * 64 + (o_base + oo)) * 64 + h) * 64 + w0)) = v;
    }
}

// shared compute block for B and C (DPP edges, kv batched per chunk)
#define COMPUTE_CHUNK(CC_)                                                    \
    do {                                                                      \
        float kv[CCH][2][9];                                                  \
        _Pragma("unroll") for (int cl = 0; cl < CCH; ++cl)                    \
            _Pragma("unroll") for (int oo = 0; oo < 2; ++oo) {                \
                const float* kp =                                             \
                    kern + ((size_t)(o_base + oo) * 64 + ((CC_) + cl)) * 9;   \
                _Pragma("unroll") for (int t = 0; t < 9; ++t)                 \
                    kv[cl][oo][t] = kp[t];                                    \
            }                                                                 \
        _Pragma("unroll") for (int cl = 0; cl < CCH; ++cl) {                  \
            float xv[3][6];                                                   \
            _Pragma("unroll") for (int r = 0; r < 3; ++r) {                   \
                const int rowid = cl * ROWS + hr + r;                         \
                float4 m = *(const float4*)(&xs[rowid * XSTR + w0]);          \
                xv[r][0] = dpp_neighbor<0x111>(m.w);                          \
                xv[r][1] = m.x; xv[r][2] = m.y;                               \
                xv[r][3] = m.z; xv[r][4] = m.w;                               \
                xv[r][5] = dpp_neighbor<0x101>(m.x);                          \
            }                                                                 \
            _Pragma("unroll") for (int oo = 0; oo < 2; ++oo) {                \
                const float* k9 = kv[cl][oo];                                 \
                _Pragma("unroll") for (int wi = 0; wi < 4; ++wi) {            \
                    float m = acc[oo][wi];                                    \
                    float t0 = xv[0][wi + 0] + k9[0];                         \
                    float t1 = xv[0][wi + 1] + k9[1];                         \
                    m = fmaxf(m, fmaxf(t0, t1));                              \
                    t0 = xv[0][wi + 2] + k9[2];                               \
                    t1 = xv[1][wi + 0] + k9[3];                               \
                    m = fmaxf(m, fmaxf(t0, t1));                              \
                    t0 = xv[1][wi + 1] + k9[4];                               \
                    t1 = xv[1][wi + 2] + k9[5];                               \
                    m = fmaxf(m, fmaxf(t0, t1));                              \
                    t0 = xv[2][wi + 0] + k9[6];                               \
                    t1 = xv[2][wi + 1] + k9[7];                               \
                    m = fmaxf(m, fmaxf(t0, t1));                              \
                    m = fmaxf(m, xv[2][wi + 2] + k9[8]);                      \
                    acc[oo][wi] = m;                                          \
                }                                                             \
            }                                                                 \
        }                                                                     \
    } while (0)

#define SETUP_COMMON                                                          \
    const int tid = threadIdx.x;                                              \
    const int wg  = tid & 15;                                                 \
    const int hr  = tid >> 4;                                                 \
    const int w0  = wg << 2;                                                  \
    const int h_base = blockIdx.x * HB;                                       \
    const int b      = blockIdx.y;                                            \
    const int o_base = blockIdx.z << 1;                                       \
    const float* xb = x + (size_t)b * 64 * 64 * 64;                           \
    const float* gsrc[SLOTS];                                                 \
    float*       xdst[SLOTS];                                                 \
    bool         vmask[SLOTS];                                                \
    _Pragma("unroll") for (int k = 0; k < SLOTS; ++k) {                       \
        int rowid = k * 4 + hr;                                               \
        int cl    = rowid / ROWS;                                             \
        int r     = rowid - cl * ROWS;                                        \
        int gh    = h_base + r - 1;                                           \
        bool valid = (unsigned)gh < 64u;                                      \
        int  ghc   = valid ? gh : 0;                                          \
        gsrc[k]  = xb + ((size_t)cl * 64 + ghc) * 64 + wg * 4;                \
        xdst[k]  = &xs[rowid * XSTR + wg * 4];                                \
        vmask[k] = valid;                                                     \
    }                                                                         \
    float acc[2][4];                                                          \
    _Pragma("unroll") for (int oo = 0; oo < 2; ++oo)                          \
        _Pragma("unroll") for (int wi = 0; wi < 4; ++wi)                      \
            acc[oo][wi] = NEG_INF;

#define STORE_BUF(RB_)                                                        \
    do {                                                                      \
        _Pragma("unroll") for (int k = 0; k < SLOTS; ++k) {                   \
            float4 v = RB_[k];                                                \
            if (!vmask[k])                                                    \
                v = make_float4(NEG_INF, NEG_INF, NEG_INF, NEG_INF);          \
            *(float4*)xdst[k] = v;                                            \
        }                                                                     \
    } while (0)

#define LOAD_BUF(RB_)                                                         \
    do {                                                                      \
        _Pragma("unroll") for (int k = 0; k < SLOTS; ++k) {                   \
            RB_[k] = *(const float4*)gsrc[k];                                 \
            gsrc[k] += CCH * 64 * 64;                                         \
        }                                                                     \
    } while (0)

#define WRITE_OUT                                                             \
    do {                                                                      \
        const int h = h_base + hr;                                            \
        _Pragma("unroll") for (int oo = 0; oo < 2; ++oo) {                    \
            float4 v = make_float4(acc[oo][0], acc[oo][1],                    \
                                   acc[oo][2], acc[oo][3]);                   \
            *(float4*)(out + ((((size_t)b * 64 + (o_base + oo)) * 64 + h)     \
                              * 64 + w0)) = v;                                \
        }                                                                     \
    } while (0)

// ===================== VARIANT B: round-6 verbatim (DPP, 1-deep) ============
__global__ __launch_bounds__(64, 4)
void maxplus_b_dpp(const float* __restrict__ x, const float* __restrict__ kern,
                   float* __restrict__ out) {
    __shared__ float xs[CCH * ROWS * XSTR];   // 6144 B
    SETUP_COMMON;

    float4 R[SLOTS];
    LOAD_BUF(R);

#pragma unroll 1
    for (int cc = 0; cc < 64; cc += CCH) {
        __syncthreads();
        STORE_BUF(R);
        __syncthreads();
        if (cc + CCH < 64) LOAD_BUF(R);
        COMPUTE_CHUNK(cc);
    }
    WRITE_OUT;
}

// ===================== VARIANT C: DPP + 2-chunk-deep prefetch ===============
__global__ __launch_bounds__(64, 4)
void maxplus_c_dpp2(const float* __restrict__ x, const float* __restrict__ kern,
                    float* __restrict__ out) {
    __shared__ float xs[CCH * ROWS * XSTR];   // 6144 B
    SETUP_COMMON;

    float4 RA[SLOTS], RB[SLOTS];
    LOAD_BUF(RA);   // chunk 0 in flight
    LOAD_BUF(RB);   // chunk 1 in flight — 2-deep from here on

#pragma unroll 1
    for (int cc = 0; cc < 64; cc += 2 * CCH) {
        // chunk cc (RA)
        __syncthreads();
        STORE_BUF(RA);
        __syncthreads();
        if (cc + 2 * CCH < 64) LOAD_BUF(RA);   // chunk cc+2 in flight
        COMPUTE_CHUNK(cc);

        // chunk cc+CCH (RB)
        __syncthreads();
        STORE_BUF(RB);
        __syncthreads();
        if (cc + 3 * CCH < 64) LOAD_BUF(RB);   // chunk cc+3 in flight
        COMPUTE_CHUNK(cc + CCH);
    }
    WRITE_OUT;
}

extern "C" void kernel_launch(void* const* d_in, const int* in_sizes, int n_in,
                              void* d_out, int out_size, void* d_ws, size_t ws_size,
                              hipStream_t stream) {
    const float* x    = (const float*)d_in[0];   // [8,64,64,64]
    const float* kern = (const float*)d_in[1];   // [64,64,3,3]
    float* out = (float*)d_out;                  // [8,64,64,64]

    dim3 grid(16, 8, 32);
    dim3 block(64);
    // Measurement round (resubmit after infra failure): three independently-
    // correct variants, same stream, same container/clock. Per-dispatch
    // dur_us from rocprof = clean A/B/C. All three write identical values;
    // the last dispatch determines out.
    maxplus_a_es  <<<grid, block, 0, stream>>>(x, kern, out);
    maxplus_b_dpp <<<grid, block, 0, stream>>>(x, kern, out);
    maxplus_c_dpp2<<<grid, block, 0, stream>>>(x, kern, out);
}